// Round 18
// baseline (278.625 us; speedup 1.0000x reference)
//
#include <hip/hip_runtime.h>
#include <hip/hip_cooperative_groups.h>
#include <cstdint>
#include <math.h>

namespace cg = cooperative_groups;

#define BATCH 32
#define NPIX (512*512)        // 262144 pixels per batch
#define NB1 4096              // level-1 bins: tp bits [30:19] (tp>0 -> bit31=0)
#define NBA 2048              // select level A: tp bits [18:8]
#define NBB 256               // select level B: tp bits [7:0]
#define PXB 4096              // pixels per block (fallback path)
#define CAP 32768             // candidate capacity per batch (4 MB total)
#define LCAP 8192             // LDS-resident candidate cap in selectAB (32 KB)
#define CNTSTRIDE 32          // one cache line (128B) per batch counter

// Cooperative geometry: 1024 blocks (4/CU), 32 blocks/batch, 32 px/thread.
#define CBLK 1024
#define CPXB 8192             // pixels per block: 8 quads of 256 thr * 4 px

typedef float vfloat4 __attribute__((ext_vector_type(4)));

struct State {
    int      pfx1[BATCH];            // selected 12-bit prefix (-1 if no fg)
    uint32_t krem[BATCH];            // rank within pfx1 bin (1-based)
    uint32_t candcnt[BATCH*CNTSTRIDE];
    double   I_low[BATCH];           // sum tp     over bins < pfx1
    double   U_low[BATCH];           // sum tp^2+1 over same
    double   S_bg [BATCH];           // sum p^2 over background
    double   I_cnd[BATCH];           // sum tp     over kept candidates
    double   U_cnd[BATCH];           // sum tp^2+1 over kept candidates
};

// ===========================================================================
// COOPERATIVE FUSED KERNEL: phase1 (stream+hist+Sbg, tp held in registers)
// -> grid.sync -> scan1 (blocks 0..31) -> grid.sync -> phase2 (sums+append
// from registers). Eliminates the 32MB tpv write + 32MB read entirely.
// ===========================================================================
__global__ __launch_bounds__(256, 4)
void k_fused(const float* __restrict__ logits,
             const float* __restrict__ target,
             const float* __restrict__ eps,
             uint32_t* __restrict__ hist1,
             State* st,
             uint32_t* __restrict__ cand)
{
    cg::grid_group grid = cg::this_grid();

    __shared__ uint32_t lh[NB1];       // 16 KB (phase1 hist; scan reuses none)
    __shared__ double dred[512];       // 4 KB reductions
    __shared__ uint32_t part[256];     // 1 KB scan
    __shared__ int sBin; __shared__ uint32_t sRem;

    const int tid  = threadIdx.x;
    const int lane = tid & 63;
    const int b    = blockIdx.x >> 5;          // batch
    const int blk  = blockIdx.x & 31;          // block within batch
    const size_t nbase = (size_t)b * NPIX;
    const size_t lbase = (size_t)b * 2 * NPIX;
    const int base = blk * CPXB;

    // ---------------- Phase 1: stream, hist, Sbg; hold tp bits ------------
    for (int i = tid; i < NB1; i += 256) lh[i] = 0;
    __syncthreads();

    uint32_t tpb[32];
    double Sb0 = 0.0, Sb1 = 0.0;
#pragma unroll
    for (int it = 0; it < 8; ++it) {
        const int i0 = base + (it * 256 + tid) * 4;
        float4 l0 = *(const float4*)(logits + lbase + i0);
        float4 l1 = *(const float4*)(logits + lbase + NPIX + i0);
        float4 tt = *(const float4*)(target + nbase + i0);
        float4 ee = *(const float4*)(eps    + nbase + i0);
        float a0[4] = {l0.x, l0.y, l0.z, l0.w};
        float a1[4] = {l1.x, l1.y, l1.z, l1.w};
        float tv[4] = {tt.x, tt.y, tt.z, tt.w};
        float ev[4] = {ee.x, ee.y, ee.z, ee.w};
#pragma unroll
        for (int j = 0; j < 4; ++j) {
            const int idx = it * 4 + j;
            // 2-channel softmax == sigmoid of logit difference (verified R11).
            float p  = 1.0f / (1.0f + expf(a0[j] - a1[j]));
            float tp = p * (tv[j] + ev[j]);
            bool fg  = (tv[j] == 1.0f);
            if (fg) {
                uint32_t bits = __float_as_uint(tp);
                atomicAdd(&lh[bits >> 19], 1u);
                tpb[idx] = bits;                 // bit31 = 0
            } else {
                double pp = (double)p * (double)p;
                if (j & 1) Sb1 += pp; else Sb0 += pp;
                tpb[idx] = __float_as_uint(p) | 0x80000000u;  // bg marker
            }
        }
    }

    __syncthreads();
    {
        uint32_t* hb = hist1 + (size_t)b * NB1;
        for (int bin = tid; bin < NB1; bin += 256) {
            uint32_t v = lh[bin];
            if (v) atomicAdd(hb + bin, v);
        }
        dred[tid] = Sb0 + Sb1;
        __syncthreads();
        for (int off = 128; off > 0; off >>= 1) {
            if (tid < off) dred[tid] += dred[tid + off];
            __syncthreads();
        }
        if (tid == 0) atomicAdd(&st->S_bg[b], dred[0]);
    }

    grid.sync();

    // ---------------- Scan (blocks 0..31, one per batch) -------------------
    if (blockIdx.x < 32) {
        const int sb = blockIdx.x;
        const uint32_t* h = hist1 + (size_t)sb * NB1;
        const int t = tid;
        if (t == 0) { sBin = 0; sRem = 1; }

        const int g = NB1 / 256;   // 16
        uint32_t s = 0;
        for (int j = 0; j < g; ++j) s += h[t * g + j];
        part[t] = s;
        __syncthreads();
        for (int off = 1; off < 256; off <<= 1) {
            uint32_t v = (t >= off) ? part[t - off] : 0u;
            __syncthreads();
            part[t] += v;
            __syncthreads();
        }
        uint32_t incl = part[t], excl = incl - s;
        uint32_t total = part[255];
        if (total > 0) {
            uint32_t k = total / 2;
            if (k == 0) k = 1;
            if (excl < k && k <= incl) {
                uint32_t run = excl;
                for (int j = 0; j < g; ++j) {
                    uint32_t c = h[t * g + j];
                    if (run < k && k <= run + c) { sBin = t * g + j; sRem = k - run; break; }
                    run += c;
                }
            }
        }
        __syncthreads();
        if (t == 0) {
            if (total == 0) { st->pfx1[sb] = -1; st->krem[sb] = 0; }
            else            { st->pfx1[sb] = sBin; st->krem[sb] = sRem; }
        }
    }

    grid.sync();

    // ---------------- Phase 2: sums + candidate append from registers ------
    const int pfx = st->pfx1[b];
    uint32_t predmask = 0;
    double Il = 0.0, Ul = 0.0;
#pragma unroll
    for (int idx = 0; idx < 32; ++idx) {
        uint32_t bits = tpb[idx];
        if (!(bits >> 31)) {                    // foreground
            int bin = (int)(bits >> 19);
            if (bin < pfx) {
                float tp = __uint_as_float(bits);
                Il += (double)tp;
                Ul += (double)tp * (double)tp + 1.0;
            } else if (bin == pfx) {
                predmask |= (1u << idx);
            }
        }
    }

    // Wave-aggregated append: ONE returning atomic per wave.
    uint32_t c = (uint32_t)__popc(predmask);
    uint32_t inc = c;
#pragma unroll
    for (int off = 1; off < 64; off <<= 1) {
        uint32_t v = __shfl_up(inc, off);
        if (lane >= off) inc += v;
    }
    uint32_t excl2 = inc - c;
    uint32_t wtotal = __shfl(inc, 63);
    uint32_t basec = 0;
    if (lane == 0 && wtotal) basec = atomicAdd(&st->candcnt[b * CNTSTRIDE], wtotal);
    basec = __shfl(basec, 0);

    uint32_t* cb = cand + (size_t)b * CAP;
    uint32_t pos = basec + excl2;
#pragma unroll
    for (int idx = 0; idx < 32; ++idx) {
        if ((predmask >> idx) & 1u) {
            if (pos < CAP) cb[pos] = tpb[idx];
            pos++;
        }
    }

    dred[tid] = Il; dred[256 + tid] = Ul;
    __syncthreads();
    for (int off = 128; off > 0; off >>= 1) {
        if (tid < off) { dred[tid] += dred[tid+off]; dred[256+tid] += dred[256+tid+off]; }
        __syncthreads();
    }
    if (tid == 0) {
        atomicAdd(&st->I_low[b], dred[0]);
        atomicAdd(&st->U_low[b], dred[256]);
    }
}

// ===========================================================================
// FALLBACK PATH (verified R16 kernels) — used if co-residency not available.
// ===========================================================================
__global__ __launch_bounds__(256)
void k_pass1(const float* __restrict__ logits,
             const float* __restrict__ target,
             const float* __restrict__ eps,
             float* __restrict__ tpv,
             uint32_t* __restrict__ hist1,
             State* st)
{
    __shared__ uint32_t lh[NB1];           // 16 KB
    const int tid = threadIdx.x;
    for (int i = tid; i < NB1; i += 256) lh[i] = 0;
    __syncthreads();

    const int b = blockIdx.y;
    const size_t nbase = (size_t)b * NPIX;
    const size_t lbase = (size_t)b * 2 * NPIX;
    const int base = blockIdx.x * PXB;

    float4 L0[4], L1[4], T4[4], E4[4];
#pragma unroll
    for (int it = 0; it < 4; ++it) {
        const int i0 = base + (it * 256 + tid) * 4;
        L0[it] = *(const float4*)(logits + lbase + i0);
        L1[it] = *(const float4*)(logits + lbase + NPIX + i0);
        T4[it] = *(const float4*)(target + nbase + i0);
        E4[it] = *(const float4*)(eps    + nbase + i0);
    }

    double Sb0 = 0.0, Sb1 = 0.0;
#pragma unroll
    for (int it = 0; it < 4; ++it) {
        const int i0 = base + (it * 256 + tid) * 4;
        float a0[4] = {L0[it].x, L0[it].y, L0[it].z, L0[it].w};
        float a1[4] = {L1[it].x, L1[it].y, L1[it].z, L1[it].w};
        float tv[4] = {T4[it].x, T4[it].y, T4[it].z, T4[it].w};
        float ev[4] = {E4[it].x, E4[it].y, E4[it].z, E4[it].w};
        vfloat4 vv;
#pragma unroll
        for (int j = 0; j < 4; ++j) {
            float p  = 1.0f / (1.0f + expf(a0[j] - a1[j]));
            float tp = p * (tv[j] + ev[j]);
            bool fg  = (tv[j] == 1.0f);
            if (fg) {
                atomicAdd(&lh[__float_as_uint(tp) >> 19], 1u);
                vv[j] = tp;
            } else {
                double pp = (double)p * (double)p;
                if (j & 1) Sb1 += pp; else Sb0 += pp;
                vv[j] = -p;
            }
        }
        __builtin_nontemporal_store(vv, (vfloat4*)(tpv + nbase + i0));
    }

    __syncthreads();
    uint32_t* hb = hist1 + (size_t)b * NB1;
    for (int bin = tid; bin < NB1; bin += 256) {
        uint32_t v = lh[bin];
        if (v) atomicAdd(hb + bin, v);
    }

    __shared__ double sB[256];
    sB[tid] = Sb0 + Sb1;
    __syncthreads();
    for (int off = 128; off > 0; off >>= 1) {
        if (tid < off) sB[tid] += sB[tid + off];
        __syncthreads();
    }
    if (tid == 0) atomicAdd(&st->S_bg[b], sB[0]);
}

__global__ __launch_bounds__(256)
void k_scan1(const uint32_t* __restrict__ hist1, State* st)
{
    const int b = blockIdx.x;
    const int t = threadIdx.x;
    const uint32_t* h = hist1 + (size_t)b * NB1;
    __shared__ uint32_t part[256];
    __shared__ int sBin; __shared__ uint32_t sRem;
    if (t == 0) { sBin = 0; sRem = 1; }

    const int g = NB1 / 256;   // 16
    uint32_t s = 0;
    for (int j = 0; j < g; ++j) s += h[t * g + j];
    part[t] = s;
    __syncthreads();
    for (int off = 1; off < 256; off <<= 1) {
        uint32_t v = (t >= off) ? part[t - off] : 0u;
        __syncthreads();
        part[t] += v;
        __syncthreads();
    }
    uint32_t incl = part[t], excl = incl - s;
    uint32_t total = part[255];
    if (total == 0) {
        if (t == 0) { st->pfx1[b] = -1; st->krem[b] = 0; }
        return;
    }
    uint32_t k = total / 2;
    if (k == 0) k = 1;

    if (excl < k && k <= incl) {
        uint32_t run = excl;
        for (int j = 0; j < g; ++j) {
            uint32_t c = h[t * g + j];
            if (run < k && k <= run + c) { sBin = t * g + j; sRem = k - run; break; }
            run += c;
        }
    }
    __syncthreads();
    if (t == 0) { st->pfx1[b] = sBin; st->krem[b] = sRem; }
}

__global__ __launch_bounds__(256)
void k_pass2(const float* __restrict__ tpv,
             State* st, uint32_t* __restrict__ cand)
{
    const int b = blockIdx.y;
    const int tid = threadIdx.x;
    const int lane = tid & 63;
    const int pfx = st->pfx1[b];
    const size_t nbase = (size_t)b * NPIX;
    const int base = blockIdx.x * PXB;
    uint32_t* cb = cand + (size_t)b * CAP;

    float4 V4[4];
#pragma unroll
    for (int it = 0; it < 4; ++it) {
        const int i0 = base + (it * 256 + tid) * 4;
        V4[it] = *(const float4*)(tpv + nbase + i0);
    }

    uint32_t tpb_[16];
    uint32_t predmask = 0;
    double Il = 0.0, Ul = 0.0;
#pragma unroll
    for (int it = 0; it < 4; ++it) {
        float vv[4] = {V4[it].x, V4[it].y, V4[it].z, V4[it].w};
#pragma unroll
        for (int j = 0; j < 4; ++j) {
            const int idx = it * 4 + j;
            uint32_t bits = __float_as_uint(vv[j]);
            tpb_[idx] = bits;
            if (!(bits >> 31)) {
                int bin = (int)(bits >> 19);
                if (bin < pfx) {
                    float tp = vv[j];
                    Il += (double)tp;
                    Ul += (double)tp * (double)tp + 1.0;
                } else if (bin == pfx) {
                    predmask |= (1u << idx);
                }
            }
        }
    }

    uint32_t c = (uint32_t)__popc(predmask);
    uint32_t inc = c;
#pragma unroll
    for (int off = 1; off < 64; off <<= 1) {
        uint32_t v = __shfl_up(inc, off);
        if (lane >= off) inc += v;
    }
    uint32_t excl = inc - c;
    uint32_t wtotal = __shfl(inc, 63);
    uint32_t basec = 0;
    if (lane == 0 && wtotal) basec = atomicAdd(&st->candcnt[b * CNTSTRIDE], wtotal);
    basec = __shfl(basec, 0);

    uint32_t pos = basec + excl;
#pragma unroll
    for (int idx = 0; idx < 16; ++idx) {
        if ((predmask >> idx) & 1u) {
            if (pos < CAP) cb[pos] = tpb_[idx];
            pos++;
        }
    }

    __shared__ double sI[256];
    __shared__ double sU[256];
    sI[tid] = Il; sU[tid] = Ul;
    __syncthreads();
    for (int off = 128; off > 0; off >>= 1) {
        if (tid < off) { sI[tid] += sI[tid+off]; sU[tid] += sU[tid+off]; }
        __syncthreads();
    }
    if (tid == 0) {
        atomicAdd(&st->I_low[b], sI[0]);
        atomicAdd(&st->U_low[b], sU[0]);
    }
}

// ---------------------------------------------------------------------------
#define SELECT_BIN_L(ld, nb, k)                                               \
    {                                                                         \
        const int g = (nb) / 256;                                             \
        uint32_t s = 0;                                                       \
        for (int j = 0; j < g; ++j) s += (ld)[t * g + j];                     \
        part[t] = s;                                                          \
        __syncthreads();                                                      \
        for (int off = 1; off < 256; off <<= 1) {                             \
            uint32_t v = (t >= off) ? part[t - off] : 0u;                     \
            __syncthreads();                                                  \
            part[t] += v;                                                     \
            __syncthreads();                                                  \
        }                                                                     \
        uint32_t incl = part[t], excl = incl - s;                             \
        if (excl < (k) && (k) <= incl) {                                      \
            uint32_t run = excl;                                              \
            for (int j = 0; j < g; ++j) {                                     \
                uint32_t c = (ld)[t * g + j];                                 \
                if (run < (k) && (k) <= run + c) {                            \
                    sBin = t * g + j;                                         \
                    sRem = (k) - run;                                         \
                    break;                                                    \
                }                                                             \
            }                                                                 \
        }                                                                     \
        __syncthreads();                                                      \
    }

__global__ __launch_bounds__(256)
void k_selectAB(State* st, const uint32_t* __restrict__ cand)
{
    const int b = blockIdx.x;
    const int t = threadIdx.x;
    const int pfx = st->pfx1[b];
    if (pfx < 0) return;                   // I_cnd/U_cnd stay 0 (memset)
    const uint32_t kA = st->krem[b];
    const uint32_t n = min(st->candcnt[b * CNTSTRIDE], (uint32_t)CAP);
    const uint32_t* cb = cand + (size_t)b * CAP;

    __shared__ uint32_t cstore[LCAP];      // 32 KB
    __shared__ uint32_t lh[NBA];           // 8 KB (reused for level B)
    __shared__ uint32_t part[256];
    __shared__ int sBin; __shared__ uint32_t sRem;

    const bool inLDS = (n <= (uint32_t)LCAP);
    if (inLDS) {
        for (uint32_t i = t; i < n; i += 256) cstore[i] = cb[i];
    }

    for (int i = t; i < NBA; i += 256) lh[i] = 0;
    if (t == 0) { sBin = 0; sRem = 1; }
    __syncthreads();
    for (uint32_t i = t; i < n; i += 256) {
        uint32_t bits = inLDS ? cstore[i] : cb[i];
        atomicAdd(&lh[(bits >> 8) & (NBA - 1)], 1u);
    }
    __syncthreads();
    SELECT_BIN_L(lh, NBA, kA);
    const uint32_t binA = (uint32_t)sBin;
    const uint32_t kB = sRem;
    __syncthreads();

    for (int i = t; i < NBB; i += 256) lh[i] = 0;
    if (t == 0) { sBin = 0; sRem = 1; }
    __syncthreads();
    for (uint32_t i = t; i < n; i += 256) {
        uint32_t bits = inLDS ? cstore[i] : cb[i];
        if (((bits >> 8) & (NBA - 1)) == binA)
            atomicAdd(&lh[bits & (NBB - 1)], 1u);
    }
    __syncthreads();
    SELECT_BIN_L(lh, NBB, kB);
    const uint32_t binB = (uint32_t)sBin;
    const uint32_t thr_bits = ((uint32_t)pfx << 19) | (binA << 8) | binB;

    double I = 0.0, U = 0.0;
    for (uint32_t i = t; i < n; i += 256) {
        uint32_t bits = inLDS ? cstore[i] : cb[i];
        if (bits <= thr_bits) {
            float tp = __uint_as_float(bits);
            I += (double)tp;
            U += (double)tp * (double)tp + 1.0;
        }
    }
    __shared__ double sI[256];
    __shared__ double sU[256];
    sI[t] = I; sU[t] = U;
    __syncthreads();
    for (int off = 128; off > 0; off >>= 1) {
        if (t < off) { sI[t] += sI[t+off]; sU[t] += sU[t+off]; }
        __syncthreads();
    }
    if (t == 0) {
        st->I_cnd[b] = sI[0];
        st->U_cnd[b] = sU[0];
    }
}

__global__ void k_finalize(const State* __restrict__ st, float* __restrict__ out)
{
    const int t = threadIdx.x;
    double d = 0.0;
    if (t < BATCH) {
        double I = st->I_low[t] + st->I_cnd[t];
        double U = st->U_low[t] + st->U_cnd[t] + st->S_bg[t];
        d = (2.0 * I + 1e-5) / (U + 1e-5);
    }
    for (int off = 32; off > 0; off >>= 1) d += __shfl_down(d, off);
    if (t == 0) out[0] = (float)(1.0 - d / (double)BATCH);
}

// ---------------------------------------------------------------------------
extern "C" void kernel_launch(void* const* d_in, const int* in_sizes, int n_in,
                              void* d_out, int out_size, void* d_ws, size_t ws_size,
                              hipStream_t stream) {
    const float* logits = (const float*)d_in[0];
    const float* target = (const float*)d_in[1];
    const float* eps    = (const float*)d_in[2];
    float* out = (float*)d_out;

    char* ws = (char*)d_ws;
    size_t off = 0;
    uint32_t* hist1 = (uint32_t*)(ws + off); off += (size_t)BATCH * NB1 * 4;   // 512 KB
    State*    st    = (State*)   (ws + off); off += sizeof(State);
    const size_t baseNeed = off;

    off = ((off + 255) / 256) * 256;
    uint32_t* cand = (uint32_t*)(ws + off); off += (size_t)BATCH * CAP * 4;    // 4 MB
    float*    tpv  = (float*)   (ws + off); off += (size_t)BATCH * NPIX * 4;   // 32 MB (fallback only)

    // Zero histogram + state each call (graph-capture safe).
    hipMemsetAsync(ws, 0, baseNeed, stream);

    // Co-residency check for the cooperative path (host query, capture-safe,
    // deterministic for a fixed device/binary).
    int blocksPerCU = 0;
    hipError_t qerr = hipOccupancyMaxActiveBlocksPerMultiprocessor(
        &blocksPerCU, (const void*)k_fused, 256, 0);
    hipDeviceProp_t props;
    int dev = 0;
    hipGetDevice(&dev);
    hipGetDeviceProperties(&props, dev);
    const bool coopOK = (qerr == hipSuccess) &&
                        ((long long)blocksPerCU * props.multiProcessorCount >= CBLK);

    if (coopOK) {
        void* args[] = { (void*)&logits, (void*)&target, (void*)&eps,
                         (void*)&hist1, (void*)&st, (void*)&cand };
        hipLaunchCooperativeKernel((const void*)k_fused,
                                   dim3(CBLK), dim3(256), args, 0, stream);
    } else {
        dim3 grid(NPIX / PXB, BATCH);   // 64 x 32 = 2048 blocks
        k_pass1<<<grid, 256, 0, stream>>>(logits, target, eps, tpv, hist1, st);
        k_scan1<<<BATCH, 256, 0, stream>>>(hist1, st);
        k_pass2<<<grid, 256, 0, stream>>>(tpv, st, cand);
    }
    k_selectAB<<<BATCH, 256, 0, stream>>>(st, cand);
    k_finalize<<<1, 64, 0, stream>>>(st, out);
}

// Round 19
// 76.295 us; speedup vs baseline: 3.6520x; 3.6520x over previous
//
#include <hip/hip_runtime.h>
#include <cstdint>
#include <math.h>

#define BATCH 32
#define NPIX (512*512)        // 262144 pixels per batch
#define NB1 4096              // level-1 bins: tp bits [30:19] (tp>0 -> bit31=0)
#define NBA 2048              // select level A: tp bits [18:8]
#define NBB 256               // select level B: tp bits [7:0]
#define PXB 4096              // pixels per block (256 thr * 16 px)
#define CAP 32768             // candidate capacity per batch (4 MB total)
#define LCAP 8192             // LDS-resident candidate cap in selectAB (32 KB)
#define CNTSTRIDE 32          // one cache line (128B) per batch counter

typedef float vfloat4 __attribute__((ext_vector_type(4)));

struct State {
    int      pfx1[BATCH];            // selected 12-bit prefix (-1 if no fg)
    uint32_t krem[BATCH];            // rank within pfx1 bin (1-based)
    uint32_t candcnt[BATCH*CNTSTRIDE];
    double   I_low[BATCH];           // sum tp     over bins < pfx1
    double   U_low[BATCH];           // sum tp^2+1 over same
    double   S_bg [BATCH];           // sum p^2 over background
    double   I_cnd[BATCH];           // sum tp     over kept candidates
    double   U_cnd[BATCH];           // sum tp^2+1 over kept candidates
};

// ---------------------------------------------------------------------------
// Pass 1 (hot; R16-verified fastest form): read 128 MB, sigmoid softmax,
// nt-store tpv (fg->tp, bg->-p), 4096-bin LDS count histogram, Sbg in f64
// registers. No append machinery (measured: any addition costs 4-20 us).
// ---------------------------------------------------------------------------
__global__ __launch_bounds__(256)
void k_pass1(const float* __restrict__ logits,
             const float* __restrict__ target,
             const float* __restrict__ eps,
             float* __restrict__ tpv,
             uint32_t* __restrict__ hist1,
             State* st)
{
    __shared__ uint32_t lh[NB1];           // 16 KB
    const int tid = threadIdx.x;
    for (int i = tid; i < NB1; i += 256) lh[i] = 0;
    __syncthreads();

    const int b = blockIdx.y;
    const size_t nbase = (size_t)b * NPIX;
    const size_t lbase = (size_t)b * 2 * NPIX;
    const int base = blockIdx.x * PXB;

    float4 L0[4], L1[4], T4[4], E4[4];
#pragma unroll
    for (int it = 0; it < 4; ++it) {
        const int i0 = base + (it * 256 + tid) * 4;
        L0[it] = *(const float4*)(logits + lbase + i0);
        L1[it] = *(const float4*)(logits + lbase + NPIX + i0);
        T4[it] = *(const float4*)(target + nbase + i0);
        E4[it] = *(const float4*)(eps    + nbase + i0);
    }

    double Sb0 = 0.0, Sb1 = 0.0;
#pragma unroll
    for (int it = 0; it < 4; ++it) {
        const int i0 = base + (it * 256 + tid) * 4;
        float a0[4] = {L0[it].x, L0[it].y, L0[it].z, L0[it].w};
        float a1[4] = {L1[it].x, L1[it].y, L1[it].z, L1[it].w};
        float tv[4] = {T4[it].x, T4[it].y, T4[it].z, T4[it].w};
        float ev[4] = {E4[it].x, E4[it].y, E4[it].z, E4[it].w};
        vfloat4 vv;
#pragma unroll
        for (int j = 0; j < 4; ++j) {
            // 2-channel softmax == sigmoid of logit difference (verified R11).
            float p  = 1.0f / (1.0f + expf(a0[j] - a1[j]));
            float tp = p * (tv[j] + ev[j]);
            bool fg  = (tv[j] == 1.0f);
            if (fg) {
                atomicAdd(&lh[__float_as_uint(tp) >> 19], 1u);  // tp>0: 12 bits
                vv[j] = tp;              // positive
            } else {
                double pp = (double)p * (double)p;
                if (j & 1) Sb1 += pp; else Sb0 += pp;
                vv[j] = -p;              // sign bit marks background
            }
        }
        __builtin_nontemporal_store(vv, (vfloat4*)(tpv + nbase + i0));
    }

    __syncthreads();
    uint32_t* hb = hist1 + (size_t)b * NB1;
    for (int bin = tid; bin < NB1; bin += 256) {
        uint32_t v = lh[bin];
        if (v) atomicAdd(hb + bin, v);
    }

    __shared__ double sB[256];
    sB[tid] = Sb0 + Sb1;
    __syncthreads();
    for (int off = 128; off > 0; off >>= 1) {
        if (tid < off) sB[tid] += sB[tid + off];
        __syncthreads();
    }
    if (tid == 0) atomicAdd(&st->S_bg[b], sB[0]);
}

// ---------------------------------------------------------------------------
// Scan level-1 (4096 bins): pick bin containing rank k = max(1, n_fg/2).
// ---------------------------------------------------------------------------
__global__ __launch_bounds__(256)
void k_scan1(const uint32_t* __restrict__ hist1, State* st)
{
    const int b = blockIdx.x;
    const int t = threadIdx.x;
    const uint32_t* h = hist1 + (size_t)b * NB1;
    __shared__ uint32_t part[256];
    __shared__ int sBin; __shared__ uint32_t sRem;
    if (t == 0) { sBin = 0; sRem = 1; }

    const int g = NB1 / 256;   // 16
    uint32_t s = 0;
    for (int j = 0; j < g; ++j) s += h[t * g + j];
    part[t] = s;
    __syncthreads();
    for (int off = 1; off < 256; off <<= 1) {
        uint32_t v = (t >= off) ? part[t - off] : 0u;
        __syncthreads();
        part[t] += v;
        __syncthreads();
    }
    uint32_t incl = part[t], excl = incl - s;
    uint32_t total = part[255];
    if (total == 0) {
        if (t == 0) { st->pfx1[b] = -1; st->krem[b] = 0; }
        return;
    }
    uint32_t k = total / 2;
    if (k == 0) k = 1;

    if (excl < k && k <= incl) {
        uint32_t run = excl;
        for (int j = 0; j < g; ++j) {
            uint32_t c = h[t * g + j];
            if (run < k && k <= run + c) { sBin = t * g + j; sRem = k - run; break; }
            run += c;
        }
    }
    __syncthreads();
    if (t == 0) { st->pfx1[b] = sBin; st->krem[b] = sRem; }
}

// ---------------------------------------------------------------------------
// Pass 2: read tpv (32 MB, L3-warm). fg bin<pfx1 -> I/U_low register sums;
// bin==pfx1 -> wave-aggregated candidate append.
// ---------------------------------------------------------------------------
__global__ __launch_bounds__(256)
void k_pass2(const float* __restrict__ tpv,
             State* st, uint32_t* __restrict__ cand)
{
    const int b = blockIdx.y;
    const int tid = threadIdx.x;
    const int lane = tid & 63;
    const int pfx = st->pfx1[b];     // -1: no bin matches (bin >= 0)
    const size_t nbase = (size_t)b * NPIX;
    const int base = blockIdx.x * PXB;
    uint32_t* cb = cand + (size_t)b * CAP;

    float4 V4[4];
#pragma unroll
    for (int it = 0; it < 4; ++it) {
        const int i0 = base + (it * 256 + tid) * 4;
        V4[it] = *(const float4*)(tpv + nbase + i0);
    }

    uint32_t tpb_[16];
    uint32_t predmask = 0;
    double Il = 0.0, Ul = 0.0;
#pragma unroll
    for (int it = 0; it < 4; ++it) {
        float vv[4] = {V4[it].x, V4[it].y, V4[it].z, V4[it].w};
#pragma unroll
        for (int j = 0; j < 4; ++j) {
            const int idx = it * 4 + j;
            uint32_t bits = __float_as_uint(vv[j]);
            tpb_[idx] = bits;
            if (!(bits >> 31)) {                    // foreground: tp
                int bin = (int)(bits >> 19);
                if (bin < pfx) {
                    float tp = vv[j];
                    Il += (double)tp;
                    Ul += (double)tp * (double)tp + 1.0;
                } else if (bin == pfx) {
                    predmask |= (1u << idx);
                }
            }
        }
    }

    // Wave-aggregated append: ONE returning atomic per wave.
    uint32_t c = (uint32_t)__popc(predmask);
    uint32_t inc = c;
#pragma unroll
    for (int off = 1; off < 64; off <<= 1) {
        uint32_t v = __shfl_up(inc, off);
        if (lane >= off) inc += v;
    }
    uint32_t excl = inc - c;
    uint32_t wtotal = __shfl(inc, 63);
    uint32_t basec = 0;
    if (lane == 0 && wtotal) basec = atomicAdd(&st->candcnt[b * CNTSTRIDE], wtotal);
    basec = __shfl(basec, 0);

    uint32_t pos = basec + excl;
#pragma unroll
    for (int idx = 0; idx < 16; ++idx) {
        if ((predmask >> idx) & 1u) {
            if (pos < CAP) cb[pos] = tpb_[idx];
            pos++;
        }
    }

    __shared__ double sI[256];
    __shared__ double sU[256];
    sI[tid] = Il; sU[tid] = Ul;
    __syncthreads();
    for (int off = 128; off > 0; off >>= 1) {
        if (tid < off) { sI[tid] += sI[tid+off]; sU[tid] += sU[tid+off]; }
        __syncthreads();
    }
    if (tid == 0) {
        atomicAdd(&st->I_low[b], sI[0]);
        atomicAdd(&st->U_low[b], sU[0]);
    }
}

// ---------------------------------------------------------------------------
#define SELECT_BIN_L(ld, nb, k)                                               \
    {                                                                         \
        const int g = (nb) / 256;                                             \
        uint32_t s = 0;                                                       \
        for (int j = 0; j < g; ++j) s += (ld)[t * g + j];                     \
        part[t] = s;                                                          \
        __syncthreads();                                                      \
        for (int off = 1; off < 256; off <<= 1) {                             \
            uint32_t v = (t >= off) ? part[t - off] : 0u;                     \
            __syncthreads();                                                  \
            part[t] += v;                                                     \
            __syncthreads();                                                  \
        }                                                                     \
        uint32_t incl = part[t], excl = incl - s;                             \
        if (excl < (k) && (k) <= incl) {                                      \
            uint32_t run = excl;                                              \
            for (int j = 0; j < g; ++j) {                                     \
                uint32_t c = (ld)[t * g + j];                                 \
                if (run < (k) && (k) <= run + c) {                            \
                    sBin = t * g + j;                                         \
                    sRem = (k) - run;                                         \
                    break;                                                    \
                }                                                             \
            }                                                                 \
        }                                                                     \
        __syncthreads();                                                      \
    }

// ---------------------------------------------------------------------------
// Fused select, LDS-resident (verified R16): copy candidate list into LDS
// once; level A (bits[18:8]) -> binA; level B (bits[7:0]) -> binB -> thr;
// kept sums. One block per batch; global fallback if n > LCAP.
// ---------------------------------------------------------------------------
__global__ __launch_bounds__(256)
void k_selectAB(State* st, const uint32_t* __restrict__ cand)
{
    const int b = blockIdx.x;
    const int t = threadIdx.x;
    const int pfx = st->pfx1[b];
    if (pfx < 0) return;                   // I_cnd/U_cnd stay 0 (memset)
    const uint32_t kA = st->krem[b];
    const uint32_t n = min(st->candcnt[b * CNTSTRIDE], (uint32_t)CAP);
    const uint32_t* cb = cand + (size_t)b * CAP;

    __shared__ uint32_t cstore[LCAP];      // 32 KB
    __shared__ uint32_t lh[NBA];           // 8 KB (reused for level B)
    __shared__ uint32_t part[256];
    __shared__ int sBin; __shared__ uint32_t sRem;

    const bool inLDS = (n <= (uint32_t)LCAP);
    if (inLDS) {
        for (uint32_t i = t; i < n; i += 256) cstore[i] = cb[i];
    }

    for (int i = t; i < NBA; i += 256) lh[i] = 0;
    if (t == 0) { sBin = 0; sRem = 1; }
    __syncthreads();
    for (uint32_t i = t; i < n; i += 256) {
        uint32_t bits = inLDS ? cstore[i] : cb[i];
        atomicAdd(&lh[(bits >> 8) & (NBA - 1)], 1u);
    }
    __syncthreads();
    SELECT_BIN_L(lh, NBA, kA);
    const uint32_t binA = (uint32_t)sBin;
    const uint32_t kB = sRem;
    __syncthreads();

    for (int i = t; i < NBB; i += 256) lh[i] = 0;
    if (t == 0) { sBin = 0; sRem = 1; }
    __syncthreads();
    for (uint32_t i = t; i < n; i += 256) {
        uint32_t bits = inLDS ? cstore[i] : cb[i];
        if (((bits >> 8) & (NBA - 1)) == binA)
            atomicAdd(&lh[bits & (NBB - 1)], 1u);
    }
    __syncthreads();
    SELECT_BIN_L(lh, NBB, kB);
    const uint32_t binB = (uint32_t)sBin;
    const uint32_t thr_bits = ((uint32_t)pfx << 19) | (binA << 8) | binB;

    double I = 0.0, U = 0.0;
    for (uint32_t i = t; i < n; i += 256) {
        uint32_t bits = inLDS ? cstore[i] : cb[i];
        if (bits <= thr_bits) {
            float tp = __uint_as_float(bits);
            I += (double)tp;
            U += (double)tp * (double)tp + 1.0;
        }
    }
    __shared__ double sI[256];
    __shared__ double sU[256];
    sI[t] = I; sU[t] = U;
    __syncthreads();
    for (int off = 128; off > 0; off >>= 1) {
        if (t < off) { sI[t] += sI[t+off]; sU[t] += sU[t+off]; }
        __syncthreads();
    }
    if (t == 0) {
        st->I_cnd[b] = sI[0];              // single block per batch
        st->U_cnd[b] = sU[0];
    }
}

__global__ void k_finalize(const State* __restrict__ st, float* __restrict__ out)
{
    const int t = threadIdx.x;
    double d = 0.0;
    if (t < BATCH) {
        double I = st->I_low[t] + st->I_cnd[t];
        double U = st->U_low[t] + st->U_cnd[t] + st->S_bg[t];
        d = (2.0 * I + 1e-5) / (U + 1e-5);
    }
    for (int off = 32; off > 0; off >>= 1) d += __shfl_down(d, off);
    if (t == 0) out[0] = (float)(1.0 - d / (double)BATCH);
}

// ---------------------------------------------------------------------------
extern "C" void kernel_launch(void* const* d_in, const int* in_sizes, int n_in,
                              void* d_out, int out_size, void* d_ws, size_t ws_size,
                              hipStream_t stream) {
    const float* logits = (const float*)d_in[0];
    const float* target = (const float*)d_in[1];
    const float* eps    = (const float*)d_in[2];
    float* out = (float*)d_out;

    char* ws = (char*)d_ws;
    size_t off = 0;
    uint32_t* hist1 = (uint32_t*)(ws + off); off += (size_t)BATCH * NB1 * 4;   // 512 KB
    State*    st    = (State*)   (ws + off); off += sizeof(State);
    const size_t baseNeed = off;

    off = ((off + 255) / 256) * 256;
    uint32_t* cand = (uint32_t*)(ws + off); off += (size_t)BATCH * CAP * 4;    // 4 MB
    float*    tpv  = (float*)   (ws + off); off += (size_t)BATCH * NPIX * 4;   // 32 MB

    // Zero histogram + state each call (graph-capture safe).
    hipMemsetAsync(ws, 0, baseNeed, stream);

    dim3 grid(NPIX / PXB, BATCH);   // 64 x 32 = 2048 blocks
    k_pass1   <<<grid, 256, 0, stream>>>(logits, target, eps, tpv, hist1, st);
    k_scan1   <<<BATCH, 256, 0, stream>>>(hist1, st);
    k_pass2   <<<grid, 256, 0, stream>>>(tpv, st, cand);
    k_selectAB<<<BATCH, 256, 0, stream>>>(st, cand);
    k_finalize<<<1, 64, 0, stream>>>(st, out);
}

// Round 20
// 67.081 us; speedup vs baseline: 4.1536x; 1.1374x over previous
//
#include <hip/hip_runtime.h>
#include <cstdint>
#include <math.h>

#define BATCH 32
#define NPIX (512*512)        // 262144 pixels per batch
#define NB1 4096              // level-1 bins: tp bits [30:19] (tp>0 -> bit31=0)
#define NBA 2048              // select level A: tp bits [18:8]
#define NBB 256               // select level B: tp bits [7:0]
#define PXB 4096              // pixels per chunk (256 thr * 16 px)
#define NCHUNK 2              // chunks per block (grid-stride)
#define CAP 32768             // candidate capacity per batch (4 MB total)
#define LCAP 8192             // LDS-resident candidate cap in selectAB (32 KB)
#define CNTSTRIDE 32          // one cache line (128B) per batch counter

typedef float vfloat4 __attribute__((ext_vector_type(4)));

struct State {
    int      pfx1[BATCH];            // selected 12-bit prefix (-1 if no fg)
    uint32_t krem[BATCH];            // rank within pfx1 bin (1-based)
    uint32_t candcnt[BATCH*CNTSTRIDE];
    double   I_low[BATCH];           // sum tp     over bins < pfx1
    double   U_low[BATCH];           // sum tp^2+1 over same
    double   S_bg [BATCH];           // sum p^2 over background
    double   I_cnd[BATCH];           // sum tp     over kept candidates
    double   U_cnd[BATCH];           // sum tp^2+1 over kept candidates
};

// ---------------------------------------------------------------------------
// Pass 1 (hot; R16-verified algorithm, grid-strided x2): read 128 MB, sigmoid
// softmax, nt-store tpv (fg->tp, bg->-p), 4096-bin LDS count histogram
// (init/flush amortized over NCHUNK chunks), Sbg in f64 registers.
// ---------------------------------------------------------------------------
__global__ __launch_bounds__(256)
void k_pass1(const float* __restrict__ logits,
             const float* __restrict__ target,
             const float* __restrict__ eps,
             float* __restrict__ tpv,
             uint32_t* __restrict__ hist1,
             State* st)
{
    __shared__ uint32_t lh[NB1];           // 16 KB
    const int tid = threadIdx.x;
    for (int i = tid; i < NB1; i += 256) lh[i] = 0;
    __syncthreads();

    const int b = blockIdx.y;
    const size_t nbase = (size_t)b * NPIX;
    const size_t lbase = (size_t)b * 2 * NPIX;

    double Sb0 = 0.0, Sb1 = 0.0;

    for (int ch = 0; ch < NCHUNK; ++ch) {
        const int base = (blockIdx.x + ch * gridDim.x) * PXB;

        float4 L0[4], L1[4], T4[4], E4[4];
#pragma unroll
        for (int it = 0; it < 4; ++it) {
            const int i0 = base + (it * 256 + tid) * 4;
            L0[it] = *(const float4*)(logits + lbase + i0);
            L1[it] = *(const float4*)(logits + lbase + NPIX + i0);
            T4[it] = *(const float4*)(target + nbase + i0);
            E4[it] = *(const float4*)(eps    + nbase + i0);
        }

#pragma unroll
        for (int it = 0; it < 4; ++it) {
            const int i0 = base + (it * 256 + tid) * 4;
            float a0[4] = {L0[it].x, L0[it].y, L0[it].z, L0[it].w};
            float a1[4] = {L1[it].x, L1[it].y, L1[it].z, L1[it].w};
            float tv[4] = {T4[it].x, T4[it].y, T4[it].z, T4[it].w};
            float ev[4] = {E4[it].x, E4[it].y, E4[it].z, E4[it].w};
            vfloat4 vv;
#pragma unroll
            for (int j = 0; j < 4; ++j) {
                // 2-channel softmax == sigmoid of logit diff (verified R11).
                float p  = 1.0f / (1.0f + expf(a0[j] - a1[j]));
                float tp = p * (tv[j] + ev[j]);
                bool fg  = (tv[j] == 1.0f);
                if (fg) {
                    atomicAdd(&lh[__float_as_uint(tp) >> 19], 1u);
                    vv[j] = tp;              // positive
                } else {
                    double pp = (double)p * (double)p;
                    if (j & 1) Sb1 += pp; else Sb0 += pp;
                    vv[j] = -p;              // sign bit marks background
                }
            }
            __builtin_nontemporal_store(vv, (vfloat4*)(tpv + nbase + i0));
        }
    }

    __syncthreads();
    uint32_t* hb = hist1 + (size_t)b * NB1;
    for (int bin = tid; bin < NB1; bin += 256) {
        uint32_t v = lh[bin];
        if (v) atomicAdd(hb + bin, v);
    }

    __shared__ double sB[256];
    sB[tid] = Sb0 + Sb1;
    __syncthreads();
    for (int off = 128; off > 0; off >>= 1) {
        if (tid < off) sB[tid] += sB[tid + off];
        __syncthreads();
    }
    if (tid == 0) atomicAdd(&st->S_bg[b], sB[0]);
}

// ---------------------------------------------------------------------------
// Scan level-1 (4096 bins): pick bin containing rank k = max(1, n_fg/2).
// ---------------------------------------------------------------------------
__global__ __launch_bounds__(256)
void k_scan1(const uint32_t* __restrict__ hist1, State* st)
{
    const int b = blockIdx.x;
    const int t = threadIdx.x;
    const uint32_t* h = hist1 + (size_t)b * NB1;
    __shared__ uint32_t part[256];
    __shared__ int sBin; __shared__ uint32_t sRem;
    if (t == 0) { sBin = 0; sRem = 1; }

    const int g = NB1 / 256;   // 16
    uint32_t s = 0;
    for (int j = 0; j < g; ++j) s += h[t * g + j];
    part[t] = s;
    __syncthreads();
    for (int off = 1; off < 256; off <<= 1) {
        uint32_t v = (t >= off) ? part[t - off] : 0u;
        __syncthreads();
        part[t] += v;
        __syncthreads();
    }
    uint32_t incl = part[t], excl = incl - s;
    uint32_t total = part[255];
    if (total == 0) {
        if (t == 0) { st->pfx1[b] = -1; st->krem[b] = 0; }
        return;
    }
    uint32_t k = total / 2;
    if (k == 0) k = 1;

    if (excl < k && k <= incl) {
        uint32_t run = excl;
        for (int j = 0; j < g; ++j) {
            uint32_t c = h[t * g + j];
            if (run < k && k <= run + c) { sBin = t * g + j; sRem = k - run; break; }
            run += c;
        }
    }
    __syncthreads();
    if (t == 0) { st->pfx1[b] = sBin; st->krem[b] = sRem; }
}

// ---------------------------------------------------------------------------
// Pass 2 (grid-strided x2): read tpv (32 MB, L3-warm). fg bin<pfx1 ->
// I/U_low register sums; bin==pfx1 -> wave-aggregated candidate append.
// ---------------------------------------------------------------------------
__global__ __launch_bounds__(256)
void k_pass2(const float* __restrict__ tpv,
             State* st, uint32_t* __restrict__ cand)
{
    const int b = blockIdx.y;
    const int tid = threadIdx.x;
    const int lane = tid & 63;
    const int pfx = st->pfx1[b];     // -1: no bin matches (bin >= 0)
    const size_t nbase = (size_t)b * NPIX;
    uint32_t* cb = cand + (size_t)b * CAP;

    double Il = 0.0, Ul = 0.0;

    for (int ch = 0; ch < NCHUNK; ++ch) {
        const int base = (blockIdx.x + ch * gridDim.x) * PXB;

        float4 V4[4];
#pragma unroll
        for (int it = 0; it < 4; ++it) {
            const int i0 = base + (it * 256 + tid) * 4;
            V4[it] = *(const float4*)(tpv + nbase + i0);
        }

        uint32_t tpb_[16];
        uint32_t predmask = 0;
#pragma unroll
        for (int it = 0; it < 4; ++it) {
            float vv[4] = {V4[it].x, V4[it].y, V4[it].z, V4[it].w};
#pragma unroll
            for (int j = 0; j < 4; ++j) {
                const int idx = it * 4 + j;
                uint32_t bits = __float_as_uint(vv[j]);
                tpb_[idx] = bits;
                if (!(bits >> 31)) {                    // foreground: tp
                    int bin = (int)(bits >> 19);
                    if (bin < pfx) {
                        float tp = vv[j];
                        Il += (double)tp;
                        Ul += (double)tp * (double)tp + 1.0;
                    } else if (bin == pfx) {
                        predmask |= (1u << idx);
                    }
                }
            }
        }

        // Wave-aggregated append: ONE returning atomic per wave per chunk.
        uint32_t c = (uint32_t)__popc(predmask);
        uint32_t inc = c;
#pragma unroll
        for (int off = 1; off < 64; off <<= 1) {
            uint32_t v = __shfl_up(inc, off);
            if (lane >= off) inc += v;
        }
        uint32_t excl = inc - c;
        uint32_t wtotal = __shfl(inc, 63);
        uint32_t basec = 0;
        if (lane == 0 && wtotal) basec = atomicAdd(&st->candcnt[b * CNTSTRIDE], wtotal);
        basec = __shfl(basec, 0);

        uint32_t pos = basec + excl;
#pragma unroll
        for (int idx = 0; idx < 16; ++idx) {
            if ((predmask >> idx) & 1u) {
                if (pos < CAP) cb[pos] = tpb_[idx];
                pos++;
            }
        }
    }

    __shared__ double sI[256];
    __shared__ double sU[256];
    sI[tid] = Il; sU[tid] = Ul;
    __syncthreads();
    for (int off = 128; off > 0; off >>= 1) {
        if (tid < off) { sI[tid] += sI[tid+off]; sU[tid] += sU[tid+off]; }
        __syncthreads();
    }
    if (tid == 0) {
        atomicAdd(&st->I_low[b], sI[0]);
        atomicAdd(&st->U_low[b], sU[0]);
    }
}

// ---------------------------------------------------------------------------
#define SELECT_BIN_L(ld, nb, k)                                               \
    {                                                                         \
        const int g = (nb) / 256;                                             \
        uint32_t s = 0;                                                       \
        for (int j = 0; j < g; ++j) s += (ld)[t * g + j];                     \
        part[t] = s;                                                          \
        __syncthreads();                                                      \
        for (int off = 1; off < 256; off <<= 1) {                             \
            uint32_t v = (t >= off) ? part[t - off] : 0u;                     \
            __syncthreads();                                                  \
            part[t] += v;                                                     \
            __syncthreads();                                                  \
        }                                                                     \
        uint32_t incl = part[t], excl = incl - s;                             \
        if (excl < (k) && (k) <= incl) {                                      \
            uint32_t run = excl;                                              \
            for (int j = 0; j < g; ++j) {                                     \
                uint32_t c = (ld)[t * g + j];                                 \
                if (run < (k) && (k) <= run + c) {                            \
                    sBin = t * g + j;                                         \
                    sRem = (k) - run;                                         \
                    break;                                                    \
                }                                                             \
            }                                                                 \
        }                                                                     \
        __syncthreads();                                                      \
    }

// ---------------------------------------------------------------------------
// Fused select, LDS-resident (verified R16/R19): copy candidate list into
// LDS once; level A (bits[18:8]) -> binA; level B (bits[7:0]) -> binB -> thr;
// kept sums. One block per batch; global fallback if n > LCAP.
// ---------------------------------------------------------------------------
__global__ __launch_bounds__(256)
void k_selectAB(State* st, const uint32_t* __restrict__ cand)
{
    const int b = blockIdx.x;
    const int t = threadIdx.x;
    const int pfx = st->pfx1[b];
    if (pfx < 0) return;                   // I_cnd/U_cnd stay 0 (memset)
    const uint32_t kA = st->krem[b];
    const uint32_t n = min(st->candcnt[b * CNTSTRIDE], (uint32_t)CAP);
    const uint32_t* cb = cand + (size_t)b * CAP;

    __shared__ uint32_t cstore[LCAP];      // 32 KB
    __shared__ uint32_t lh[NBA];           // 8 KB (reused for level B)
    __shared__ uint32_t part[256];
    __shared__ int sBin; __shared__ uint32_t sRem;

    const bool inLDS = (n <= (uint32_t)LCAP);
    if (inLDS) {
        for (uint32_t i = t; i < n; i += 256) cstore[i] = cb[i];
    }

    for (int i = t; i < NBA; i += 256) lh[i] = 0;
    if (t == 0) { sBin = 0; sRem = 1; }
    __syncthreads();
    for (uint32_t i = t; i < n; i += 256) {
        uint32_t bits = inLDS ? cstore[i] : cb[i];
        atomicAdd(&lh[(bits >> 8) & (NBA - 1)], 1u);
    }
    __syncthreads();
    SELECT_BIN_L(lh, NBA, kA);
    const uint32_t binA = (uint32_t)sBin;
    const uint32_t kB = sRem;
    __syncthreads();

    for (int i = t; i < NBB; i += 256) lh[i] = 0;
    if (t == 0) { sBin = 0; sRem = 1; }
    __syncthreads();
    for (uint32_t i = t; i < n; i += 256) {
        uint32_t bits = inLDS ? cstore[i] : cb[i];
        if (((bits >> 8) & (NBA - 1)) == binA)
            atomicAdd(&lh[bits & (NBB - 1)], 1u);
    }
    __syncthreads();
    SELECT_BIN_L(lh, NBB, kB);
    const uint32_t binB = (uint32_t)sBin;
    const uint32_t thr_bits = ((uint32_t)pfx << 19) | (binA << 8) | binB;

    double I = 0.0, U = 0.0;
    for (uint32_t i = t; i < n; i += 256) {
        uint32_t bits = inLDS ? cstore[i] : cb[i];
        if (bits <= thr_bits) {
            float tp = __uint_as_float(bits);
            I += (double)tp;
            U += (double)tp * (double)tp + 1.0;
        }
    }
    __shared__ double sI[256];
    __shared__ double sU[256];
    sI[t] = I; sU[t] = U;
    __syncthreads();
    for (int off = 128; off > 0; off >>= 1) {
        if (t < off) { sI[t] += sI[t+off]; sU[t] += sU[t+off]; }
        __syncthreads();
    }
    if (t == 0) {
        st->I_cnd[b] = sI[0];              // single block per batch
        st->U_cnd[b] = sU[0];
    }
}

__global__ void k_finalize(const State* __restrict__ st, float* __restrict__ out)
{
    const int t = threadIdx.x;
    double d = 0.0;
    if (t < BATCH) {
        double I = st->I_low[t] + st->I_cnd[t];
        double U = st->U_low[t] + st->U_cnd[t] + st->S_bg[t];
        d = (2.0 * I + 1e-5) / (U + 1e-5);
    }
    for (int off = 32; off > 0; off >>= 1) d += __shfl_down(d, off);
    if (t == 0) out[0] = (float)(1.0 - d / (double)BATCH);
}

// ---------------------------------------------------------------------------
extern "C" void kernel_launch(void* const* d_in, const int* in_sizes, int n_in,
                              void* d_out, int out_size, void* d_ws, size_t ws_size,
                              hipStream_t stream) {
    const float* logits = (const float*)d_in[0];
    const float* target = (const float*)d_in[1];
    const float* eps    = (const float*)d_in[2];
    float* out = (float*)d_out;

    char* ws = (char*)d_ws;
    size_t off = 0;
    uint32_t* hist1 = (uint32_t*)(ws + off); off += (size_t)BATCH * NB1 * 4;   // 512 KB
    State*    st    = (State*)   (ws + off); off += sizeof(State);
    const size_t baseNeed = off;

    off = ((off + 255) / 256) * 256;
    uint32_t* cand = (uint32_t*)(ws + off); off += (size_t)BATCH * CAP * 4;    // 4 MB
    float*    tpv  = (float*)   (ws + off); off += (size_t)BATCH * NPIX * 4;   // 32 MB

    // Zero histogram + state each call (graph-capture safe).
    hipMemsetAsync(ws, 0, baseNeed, stream);

    // Grid-stride x2: 1024 blocks (4/CU), each does NCHUNK=2 chunks.
    dim3 grid(NPIX / PXB / NCHUNK, BATCH);   // 32 x 32 = 1024 blocks
    k_pass1   <<<grid, 256, 0, stream>>>(logits, target, eps, tpv, hist1, st);
    k_scan1   <<<BATCH, 256, 0, stream>>>(hist1, st);
    k_pass2   <<<grid, 256, 0, stream>>>(tpv, st, cand);
    k_selectAB<<<BATCH, 256, 0, stream>>>(st, cand);
    k_finalize<<<1, 64, 0, stream>>>(st, out);
}